// Round 1
// baseline (886.351 us; speedup 1.0000x reference)
//
#include <hip/hip_runtime.h>
#include <math.h>

#define F_DIM 128
#define TM 64
#define NTHR 256

// One "SAGE layer": out[m][c] = relu( sum_f mean_k(deep[m*16+k][f]) * W[f][c]
//                                   + sum_f shallow[m][f]           * W[128+f][c]
//                                   + bias[c] )
// deep: [M*16, 128], shallow: [M, 128], W: [256, 128] row-major, out: [M, 128]
// grid = M/64 blocks, 256 threads. LDS A-tile 64x256 fp32 (64 KB), column-swizzled.
__global__ __launch_bounds__(NTHR, 2)
void layer_kernel(const float* __restrict__ deep,
                  const float* __restrict__ shallow,
                  const float* __restrict__ W,
                  const float* __restrict__ bias,
                  float* __restrict__ out)
{
    __shared__ float A[TM * 256];   // exactly 64 KiB
    const int t  = threadIdx.x;
    const int m0 = blockIdx.x * TM;

    // ---- Phase 1: mean-reduce deep blocks + load shallow into LDS ----
    {
        const int r8 = t >> 5;          // 0..7  (row group)
        const int l  = t & 31;          // 0..31 (lane within row: float4 over 128 floats)
        const int fo = l * 4;
        for (int rr = r8; rr < TM; rr += 8) {
            const int m = m0 + rr;
            const float4* dp = (const float4*)(deep + (size_t)m * 2048 + fo);
            float4 s = dp[0];
            #pragma unroll
            for (int k = 1; k < 16; ++k) {
                float4 v = dp[k * 32];   // 128 floats = 32 float4 per deep row
                s.x += v.x; s.y += v.y; s.z += v.z; s.w += v.w;
            }
            const float inv = 1.0f / 16.0f;
            float4 sh = *(const float4*)(shallow + (size_t)m * F_DIM + fo);
            const int sw = rr * 4;      // column swizzle: phys = (logical + 4*row) & 255
            *(float4*)(&A[rr * 256 + ((fo + sw) & 255)]) =
                make_float4(s.x * inv, s.y * inv, s.z * inv, s.w * inv);
            *(float4*)(&A[rr * 256 + ((128 + fo + sw) & 255)]) = sh;
        }
    }
    __syncthreads();

    // ---- Phase 2: 64x128 GEMM tile, per-thread 4 rows x 8 cols ----
    const int ty = t >> 4;   // 0..15 -> rows ty*4 + i
    const int tx = t & 15;   // 0..15 -> cols tx*8 + j
    float acc[4][8];
    #pragma unroll
    for (int i = 0; i < 4; ++i)
        #pragma unroll
        for (int j = 0; j < 8; ++j) acc[i][j] = 0.0f;

    const float* Wp = W + tx * 8;
    for (int kk = 0; kk < 256; kk += 4) {
        float4 a[4];
        #pragma unroll
        for (int i = 0; i < 4; ++i) {
            const int r = ty * 4 + i;
            a[i] = *(const float4*)(&A[r * 256 + ((kk + r * 4) & 255)]);
        }
        float4 w0[4], w1[4];
        #pragma unroll
        for (int d = 0; d < 4; ++d) {
            const float* wr = Wp + (kk + d) * F_DIM;
            w0[d] = *(const float4*)(wr);
            w1[d] = *(const float4*)(wr + 4);
        }
        #pragma unroll
        for (int i = 0; i < 4; ++i) {
            const float av0 = a[i].x, av1 = a[i].y, av2 = a[i].z, av3 = a[i].w;
            acc[i][0] += av0*w0[0].x + av1*w0[1].x + av2*w0[2].x + av3*w0[3].x;
            acc[i][1] += av0*w0[0].y + av1*w0[1].y + av2*w0[2].y + av3*w0[3].y;
            acc[i][2] += av0*w0[0].z + av1*w0[1].z + av2*w0[2].z + av3*w0[3].z;
            acc[i][3] += av0*w0[0].w + av1*w0[1].w + av2*w0[2].w + av3*w0[3].w;
            acc[i][4] += av0*w1[0].x + av1*w1[1].x + av2*w1[2].x + av3*w1[3].x;
            acc[i][5] += av0*w1[0].y + av1*w1[1].y + av2*w1[2].y + av3*w1[3].y;
            acc[i][6] += av0*w1[0].z + av1*w1[1].z + av2*w1[2].z + av3*w1[3].z;
            acc[i][7] += av0*w1[0].w + av1*w1[1].w + av2*w1[2].w + av3*w1[3].w;
        }
    }

    // ---- Epilogue: +bias, relu, store ----
    const float4 b0 = *(const float4*)(bias + tx * 8);
    const float4 b1 = *(const float4*)(bias + tx * 8 + 4);
    #pragma unroll
    for (int i = 0; i < 4; ++i) {
        const int m = m0 + ty * 4 + i;
        float4 o0 = make_float4(fmaxf(acc[i][0] + b0.x, 0.0f),
                                fmaxf(acc[i][1] + b0.y, 0.0f),
                                fmaxf(acc[i][2] + b0.z, 0.0f),
                                fmaxf(acc[i][3] + b0.w, 0.0f));
        float4 o1 = make_float4(fmaxf(acc[i][4] + b1.x, 0.0f),
                                fmaxf(acc[i][5] + b1.y, 0.0f),
                                fmaxf(acc[i][6] + b1.z, 0.0f),
                                fmaxf(acc[i][7] + b1.w, 0.0f));
        float* op = out + (size_t)m * F_DIM + tx * 8;
        *(float4*)op       = o0;
        *(float4*)(op + 4) = o1;
    }
}

// Head: z = h0 @ lin1_W + lin1_b  (z: [256,8]); BatchNorm (training stats, biased var);
// out = sigmoid(zn @ lin2_W + lin2_b)  ([256,2]). One block, 256 threads.
__global__ __launch_bounds__(NTHR)
void head_kernel(const float* __restrict__ h0,     // [256][128]
                 const float* __restrict__ l1W,    // [128][8]
                 const float* __restrict__ l1b,    // [8]
                 const float* __restrict__ gamma,  // [8]
                 const float* __restrict__ beta,   // [8]
                 const float* __restrict__ l2W,    // [8][2]
                 const float* __restrict__ l2b,    // [2]
                 float* __restrict__ out)          // [256][2]
{
    __shared__ float z[256][8];
    __shared__ float w1s[128 * 8];
    __shared__ float ps[32][8];
    __shared__ float pq[32][8];
    __shared__ float scale_s[8], shift_s[8];

    const int t  = threadIdx.x;
    const int j  = t & 7;
    const int rg = t >> 3;   // 0..31

    // stage lin1_W into LDS (1024 floats, 4 per thread)
    #pragma unroll
    for (int i = 0; i < 4; ++i) w1s[t * 4 + i] = l1W[t * 4 + i];
    __syncthreads();

    // z[b][j] for b = it*32 + rg
    const float bj = l1b[j];
    for (int it = 0; it < 8; ++it) {
        const int b = it * 32 + rg;
        const float4* hr = (const float4*)(h0 + (size_t)b * 128);
        float s = bj;
        #pragma unroll
        for (int f4 = 0; f4 < 32; ++f4) {
            float4 h = hr[f4];
            s += h.x * w1s[(f4 * 4 + 0) * 8 + j];
            s += h.y * w1s[(f4 * 4 + 1) * 8 + j];
            s += h.z * w1s[(f4 * 4 + 2) * 8 + j];
            s += h.w * w1s[(f4 * 4 + 3) * 8 + j];
        }
        z[b][j] = s;
    }
    __syncthreads();

    // partial sums over 8 rows each
    {
        float s = 0.0f, q = 0.0f;
        #pragma unroll
        for (int r = 0; r < 8; ++r) {
            float v = z[rg * 8 + r][j];
            s += v; q += v * v;
        }
        ps[rg][j] = s; pq[rg][j] = q;
    }
    __syncthreads();

    if (t < 8) {
        float s = 0.0f, q = 0.0f;
        #pragma unroll
        for (int p = 0; p < 32; ++p) { s += ps[p][t]; q += pq[p][t]; }
        const float mu  = s * (1.0f / 256.0f);
        const float var = q * (1.0f / 256.0f) - mu * mu;
        const float sc  = gamma[t] * rsqrtf(var + 1e-5f);
        scale_s[t] = sc;
        shift_s[t] = beta[t] - mu * sc;
    }
    __syncthreads();

    // final: thread t = batch row
    {
        float o0 = l2b[0], o1 = l2b[1];
        #pragma unroll
        for (int jj = 0; jj < 8; ++jj) {
            const float zn = z[t][jj] * scale_s[jj] + shift_s[jj];
            o0 += zn * l2W[jj * 2 + 0];
            o1 += zn * l2W[jj * 2 + 1];
        }
        out[t * 2 + 0] = 1.0f / (1.0f + expf(-o0));
        out[t * 2 + 1] = 1.0f / (1.0f + expf(-o1));
    }
}

extern "C" void kernel_launch(void* const* d_in, const int* in_sizes, int n_in,
                              void* d_out, int out_size, void* d_ws, size_t ws_size,
                              hipStream_t stream)
{
    const float* x0    = (const float*)d_in[0];
    const float* x1    = (const float*)d_in[1];
    const float* x2    = (const float*)d_in[2];
    const float* x3    = (const float*)d_in[3];
    const float* W0    = (const float*)d_in[4];
    const float* b0    = (const float*)d_in[5];
    const float* W1    = (const float*)d_in[6];
    const float* b1    = (const float*)d_in[7];
    const float* W2    = (const float*)d_in[8];
    const float* b2    = (const float*)d_in[9];
    const float* l1W   = (const float*)d_in[10];
    const float* l1b   = (const float*)d_in[11];
    const float* gamma = (const float*)d_in[12];
    const float* beta  = (const float*)d_in[13];
    const float* l2W   = (const float*)d_in[14];
    const float* l2b   = (const float*)d_in[15];
    float* out = (float*)d_out;

    float* h2 = (float*)d_ws;                        // 256*256*128 fp32 = 33.55 MB
    float* h1 = h2 + (size_t)256 * 256 * 128;        // 256*16*128  fp32 =  2.10 MB
    float* h0 = h1 + (size_t)256 * 16 * 128;         // 256*128     fp32 =  0.13 MB

    // Layer 3: M = 65536 rows (deep row index = m*16+k works for all layers)
    hipLaunchKernelGGL(layer_kernel, dim3(65536 / TM), dim3(NTHR), 0, stream,
                       x3, x2, W2, b2, h2);
    // Layer 2: M = 4096
    hipLaunchKernelGGL(layer_kernel, dim3(4096 / TM), dim3(NTHR), 0, stream,
                       h2, x1, W1, b1, h1);
    // Layer 1: M = 256
    hipLaunchKernelGGL(layer_kernel, dim3(256 / TM), dim3(NTHR), 0, stream,
                       h1, x0, W0, b0, h0);
    // Head
    hipLaunchKernelGGL(head_kernel, dim3(1), dim3(NTHR), 0, stream,
                       h0, l1W, l1b, gamma, beta, l2W, l2b, out);
}